// Round 1
// baseline (117.696 us; speedup 1.0000x reference)
//
#include <hip/hip_runtime.h>

// SE3 divergence-free vector field — reduced computation.
// Only nodes[:, :3] feed the output, so per edge we need just 3 values:
//   out_c = (1/(8*sqrt(8))) * w_cut(r) * sum_k silu(emb(r)@W1)[k] * (sum_u x_src[u]*W2[k][u*32+c])
// Curl is linear -> folded into the atomic accumulation directly into d_out.

#define THREADS 256

__global__ __launch_bounds__(THREADS) void se3_edge_kernel(
    const float* __restrict__ x,     // (B*N, 8)
    const float* __restrict__ pos,   // (B*N, 3)
    const int*   __restrict__ esrc,  // (E,)
    const int*   __restrict__ edst,  // (E,)
    const float* __restrict__ W1,    // (10, 64)
    const float* __restrict__ W2,    // (64, 384)
    float*       __restrict__ out,   // (B*N, 3), pre-zeroed
    int E)
{
    // W1 staged to LDS with stride 65: bank = (j*65 + k) % 32 = (j + k) % 32,
    // so lanes with the same k but different basis row j hit distinct banks.
    __shared__ float sW1[10 * 65];
    for (int t = threadIdx.x; t < 640; t += THREADS) {
        int j = t >> 6, k = t & 63;
        sW1[j * 65 + k] = W1[t];
    }
    __syncthreads();

    int e = blockIdx.x * THREADS + threadIdx.x;
    if (e >= E) return;

    int s = esrc[e];
    int d = edst[e];

    float ex = pos[3 * s + 0] - pos[3 * d + 0];
    float ey = pos[3 * s + 1] - pos[3 * d + 1];
    float ez = pos[3 * s + 2] - pos[3 * d + 2];
    float r  = sqrtf(ex * ex + ey * ey + ez * ez + 1e-18f);

    // cutoff: w_cut = exp(-1/t), t = 10*(1 - r/3); zero for r >= 3 -> whole edge is zero
    float t10 = 10.0f - (10.0f / 3.0f) * r;
    if (t10 <= 0.0f) return;
    float wcut = __expf(-1.0f / t10);

    // radial basis: values v_j = (j+1)*step, step = 3/11.  q = r/step.
    // Only j = floor(q)-1 and floor(q) can be inside (|d|<1); others contribute exactly 0.
    // C0 = 1.14136 * e^2  (the sqrt(10) normalization cancels against W1/sqrt(10)).
    const float C0 = 8.43357306907549f;
    float q  = r * (11.0f / 3.0f);
    int   jf = (int)q;                 // q >= 0 -> trunc == floor
    float da = q - (float)jf;          // d for basis jf-1, in [0, 1)
    float db = da - 1.0f;              // d for basis jf,   in [-1, 0)
    float ya = fmaxf(1.0f - da * da, 1e-7f);
    float yb = fmaxf(1.0f - db * db, 1e-7f);
    int ja = jf - 1;
    int jb = jf;                       // jf <= 10 here since r < 3 -> q < 11
    // exp(-1/1e-7) underflows to exactly 0.0f, reproducing the boundary d=+-1 zeros.
    float ea = (ja >= 0) ? C0 * __expf(-1.0f / ya) : 0.0f;
    float eb = (jb <= 9) ? C0 * __expf(-1.0f / yb) : 0.0f;
    int jac = ja < 0 ? 0 : ja;
    int jbc = jb > 9 ? 9 : jb;

    // x_src row: 8 floats, 32B aligned -> two float4 loads
    const float4* xf = reinterpret_cast<const float4*>(x + 8 * (size_t)s);
    float4 xA = xf[0];
    float4 xB = xf[1];

    const float* w1a = sW1 + jac * 65;
    const float* w1b = sW1 + jbc * 65;

    float a0 = 0.0f, a1 = 0.0f, a2 = 0.0f;
#pragma unroll 8
    for (int k = 0; k < 64; ++k) {
        float pre = ea * w1a[k] + eb * w1b[k];
        // silu
        float hk = pre * __builtin_amdgcn_rcpf(1.0f + __expf(-pre));
        const float* w2k = W2 + k * 384;   // wave-uniform address -> scalar loads
        float g0 = xA.x * w2k[0]   + xA.y * w2k[32]  + xA.z * w2k[64]  + xA.w * w2k[96]
                 + xB.x * w2k[128] + xB.y * w2k[160] + xB.z * w2k[192] + xB.w * w2k[224];
        float g1 = xA.x * w2k[1]   + xA.y * w2k[33]  + xA.z * w2k[65]  + xA.w * w2k[97]
                 + xB.x * w2k[129] + xB.y * w2k[161] + xB.z * w2k[193] + xB.w * w2k[225];
        float g2 = xA.x * w2k[2]   + xA.y * w2k[34]  + xA.z * w2k[66]  + xA.w * w2k[98]
                 + xB.x * w2k[130] + xB.y * w2k[162] + xB.z * w2k[194] + xB.w * w2k[226];
        a0 += hk * g0;
        a1 += hk * g1;
        a2 += hk * g2;
    }

    // scale: 1/sqrt(64)=1/8 from W2, 1/sqrt(8) from inv, times w_cut
    float sc = wcut * 0.04419417382415922f;  // 1/(8*sqrt(8))
    float p0 = a0 * sc, p1 = a1 * sc, p2 = a2 * sc;

    // curl folded in: curl = (psi2-psi1, psi0-psi2, psi1-psi0)
    atomicAdd(out + 3 * d + 0, p2 - p1);
    atomicAdd(out + 3 * d + 1, p0 - p2);
    atomicAdd(out + 3 * d + 2, p1 - p0);
}

extern "C" void kernel_launch(void* const* d_in, const int* in_sizes, int n_in,
                              void* d_out, int out_size, void* d_ws, size_t ws_size,
                              hipStream_t stream) {
    const float* x    = (const float*)d_in[0];
    const float* pos  = (const float*)d_in[1];
    const int*   esrc = (const int*)d_in[2];
    const int*   edst = (const int*)d_in[3];
    const float* W1   = (const float*)d_in[4];
    const float* W2   = (const float*)d_in[5];
    float* out = (float*)d_out;

    int E = in_sizes[2];

    hipMemsetAsync(d_out, 0, (size_t)out_size * sizeof(float), stream);
    int blocks = (E + THREADS - 1) / THREADS;
    se3_edge_kernel<<<blocks, THREADS, 0, stream>>>(x, pos, esrc, edst, W1, W2, out, E);
}

// Round 2
// 106.639 us; speedup vs baseline: 1.1037x; 1.1037x over previous
//
#include <hip/hip_runtime.h>

// SE3 divergence-free vector field — tabulated radial profile.
//
// Only nodes[:, :3] feed the output. Swapping the k and u sums:
//   out_c(e) = wcut(r)/(8*sqrt8) * sum_u x_src[u] * Phi[u][c](r)
//   Phi[u][c](r) = sum_k silu((emb(r)@W1)[k]) * W2[k][u*32+c]
// Phi is 24 smooth scalar functions of r on [0,3] -> build a lerp table
// on-device each call (256 KB, L2-resident), then the edge kernel is
// ~120 VALU ops + two 128B table-row gathers + 3 atomics.
// Atomics are privatized into ncopies output images (blockIdx % ncopies
// ~ XCD-local under round-robin dispatch) and reduced in a final pass.

#define THREADS 256
#define TROW 32   // padded floats per table row (24 used) -> 128 B rows

__global__ __launch_bounds__(THREADS) void se3_build_table(
    const float* __restrict__ W1,   // (10, 64)
    const float* __restrict__ W2,   // (64, 384)
    float* __restrict__ T,          // (R, TROW)
    int R)
{
    __shared__ float sW1[10 * 65];
    for (int t = threadIdx.x; t < 640; t += THREADS) {
        int j = t >> 6, k = t & 63;
        sW1[j * 65 + k] = W1[t];
    }
    __syncthreads();

    int g = blockIdx.x * THREADS + threadIdx.x;
    if (g >= R * 24) return;
    int i = g / 24;
    int j = g - i * 24;        // j = u*3 + c
    int u = j / 3, c = j - u * 3;

    float r = 3.0f * (float)i / (float)(R - 1);

    // radial bump embedding: at most 2 of 10 basis functions non-zero.
    // C0 = 1.14136*e^2 (sqrt(10) norms cancel between emb and W1).
    const float C0 = 8.43357306907549f;
    float q  = r * (11.0f / 3.0f);
    int   jf = (int)q;
    float da = q - (float)jf;
    float db = da - 1.0f;
    float ya = fmaxf(1.0f - da * da, 1e-7f);
    float yb = fmaxf(1.0f - db * db, 1e-7f);
    int ja = jf - 1, jb = jf;
    float ea = (ja >= 0) ? C0 * __expf(-1.0f / ya) : 0.0f;
    float eb = (jb <= 9) ? C0 * __expf(-1.0f / yb) : 0.0f;
    int jac = ja < 0 ? 0 : ja;
    int jbc = jb > 9 ? 9 : jb;
    const float* w1a = sW1 + jac * 65;
    const float* w1b = sW1 + jbc * 65;
    const float* w2  = W2 + u * 32 + c;

    float acc = 0.0f;
#pragma unroll 8
    for (int k = 0; k < 64; ++k) {
        float pre = ea * w1a[k] + eb * w1b[k];
        float h   = pre / (1.0f + __expf(-pre));   // silu
        acc += h * w2[k * 384];
    }
    T[i * TROW + j] = acc;
}

__global__ __launch_bounds__(THREADS) void se3_edge_kernel(
    const float* __restrict__ x,     // (B*N, 8)
    const float* __restrict__ pos,   // (B*N, 3)
    const int*   __restrict__ esrc,  // (E,)
    const int*   __restrict__ edst,  // (E,)
    const float* __restrict__ T,     // (R, TROW)
    float*       __restrict__ outbuf,// ncopies x (B*N*3), pre-zeroed
    int E, int ncopies, int outN, float rscale, int imax)
{
    int e = blockIdx.x * THREADS + threadIdx.x;
    if (e >= E) return;

    int s = esrc[e];
    int d = edst[e];

    float ex = pos[3 * s + 0] - pos[3 * d + 0];
    float ey = pos[3 * s + 1] - pos[3 * d + 1];
    float ez = pos[3 * s + 2] - pos[3 * d + 2];
    float r  = sqrtf(ex * ex + ey * ey + ez * ez + 1e-18f);

    // cutoff: zero for r >= 3 -> edge contributes nothing
    float t10 = 10.0f - (10.0f / 3.0f) * r;
    if (t10 <= 0.0f) return;
    float wcut = __expf(-1.0f / t10);

    float tq = r * rscale;
    int   i  = (int)tq;
    if (i > imax) i = imax;
    float f  = tq - (float)i;

    const float4* T0 = reinterpret_cast<const float4*>(T + (size_t)i * TROW);
    float tv0[24], tv1[24];
#pragma unroll
    for (int q4 = 0; q4 < 6; ++q4) {
        float4 v0 = T0[q4];
        float4 v1 = T0[q4 + (TROW / 4)];   // next row
        tv0[4*q4+0] = v0.x; tv0[4*q4+1] = v0.y; tv0[4*q4+2] = v0.z; tv0[4*q4+3] = v0.w;
        tv1[4*q4+0] = v1.x; tv1[4*q4+1] = v1.y; tv1[4*q4+2] = v1.z; tv1[4*q4+3] = v1.w;
    }

    const float4* xf = reinterpret_cast<const float4*>(x + 8 * (size_t)s);
    float4 xA = xf[0];
    float4 xB = xf[1];
    float xs[8] = {xA.x, xA.y, xA.z, xA.w, xB.x, xB.y, xB.z, xB.w};

    float p0 = 0.0f, p1 = 0.0f, p2 = 0.0f;
#pragma unroll
    for (int u = 0; u < 8; ++u) {
        float xu = xs[u];
        int b = 3 * u;
        p0 = fmaf(xu, fmaf(f, tv1[b+0] - tv0[b+0], tv0[b+0]), p0);
        p1 = fmaf(xu, fmaf(f, tv1[b+1] - tv0[b+1], tv0[b+1]), p1);
        p2 = fmaf(xu, fmaf(f, tv1[b+2] - tv0[b+2], tv0[b+2]), p2);
    }

    float sc = wcut * 0.04419417382415922f;  // 1/(8*sqrt(8))
    p0 *= sc; p1 *= sc; p2 *= sc;

    // curl folded in: curl = (psi2-psi1, psi0-psi2, psi1-psi0)
    float* ob = outbuf + (size_t)(blockIdx.x % ncopies) * outN + 3 * d;
    atomicAdd(ob + 0, p2 - p1);
    atomicAdd(ob + 1, p0 - p2);
    atomicAdd(ob + 2, p1 - p0);
}

__global__ __launch_bounds__(THREADS) void se3_reduce_kernel(
    const float* __restrict__ ws, float* __restrict__ out,
    int outN4, int ncopies)
{
    int idx = blockIdx.x * THREADS + threadIdx.x;
    if (idx >= outN4) return;
    const float4* w = reinterpret_cast<const float4*>(ws);
    float4 acc = w[idx];
    for (int c = 1; c < ncopies; ++c) {
        float4 v = w[(size_t)c * outN4 + idx];
        acc.x += v.x; acc.y += v.y; acc.z += v.z; acc.w += v.w;
    }
    reinterpret_cast<float4*>(out)[idx] = acc;
}

extern "C" void kernel_launch(void* const* d_in, const int* in_sizes, int n_in,
                              void* d_out, int out_size, void* d_ws, size_t ws_size,
                              hipStream_t stream) {
    const float* x    = (const float*)d_in[0];
    const float* pos  = (const float*)d_in[1];
    const int*   esrc = (const int*)d_in[2];
    const int*   edst = (const int*)d_in[3];
    const float* W1   = (const float*)d_in[4];
    const float* W2   = (const float*)d_in[5];
    float* out = (float*)d_out;

    int E    = in_sizes[2];
    int outN = out_size;  // B*N*3 = 98304

    // Table resolution: largest power-of-2 <= 2048 that fits d_ws.
    int R = 2048;
    while (R > 64 && (size_t)R * TROW * sizeof(float) > ws_size) R >>= 1;
    size_t tableFloats = (size_t)R * TROW;
    size_t tableBytes  = tableFloats * sizeof(float);

    int ncopies = 0;
    if (ws_size >= tableBytes) {
        size_t rem = ws_size - tableBytes;
        ncopies = (int)(rem / ((size_t)outN * sizeof(float)));
        if (ncopies > 8) ncopies = 8;
    }

    float* T = (float*)d_ws;
    float rscale = (float)(R - 1) / 3.0f;
    int   imax   = R - 2;

    int buildBlocks = (R * 24 + THREADS - 1) / THREADS;
    se3_build_table<<<buildBlocks, THREADS, 0, stream>>>(W1, W2, T, R);

    int edgeBlocks = (E + THREADS - 1) / THREADS;
    if (ncopies >= 2) {
        float* copies = T + tableFloats;
        hipMemsetAsync(copies, 0, (size_t)ncopies * outN * sizeof(float), stream);
        se3_edge_kernel<<<edgeBlocks, THREADS, 0, stream>>>(
            x, pos, esrc, edst, T, copies, E, ncopies, outN, rscale, imax);
        int outN4 = outN / 4;
        se3_reduce_kernel<<<(outN4 + THREADS - 1) / THREADS, THREADS, 0, stream>>>(
            copies, out, outN4, ncopies);
    } else {
        hipMemsetAsync(out, 0, (size_t)outN * sizeof(float), stream);
        se3_edge_kernel<<<edgeBlocks, THREADS, 0, stream>>>(
            x, pos, esrc, edst, T, out, E, 1, outN, rscale, imax);
    }
}

// Round 3
// 105.631 us; speedup vs baseline: 1.1142x; 1.0096x over previous
//
#include <hip/hip_runtime.h>
#include <hip/hip_fp16.h>

// SE3 divergence-free vector field — tabulated radial profile, v2.
//
// Only nodes[:, :3] feed the output:
//   out_c(e) = sum_u x_src[u] * Psi[u][c](r_e)
//   Psi[u][c](r) = wcut(r)/(8*sqrt8) * sum_k silu((emb(r)@W1)[k]) * W2[k][u*32+c]
// Psi = 24 smooth scalar functions of r on [0,3).  Table: R rows, row i holds
// 24 x half2(Psi(r_i), Psi(r_{i+1})) -> ONE 96B row gives both lerp endpoints.
// Row stride 128B (aligned float4 gathers). wcut and all scales folded in.
// Curl folded into the atomic accumulate; atomics privatized over 8 copies
// (blockIdx%8 ~ XCD-local) and reduced in a final float4 pass.

#define THREADS 256
#define RTAB 2048
#define ROWH 64   // halves per row (48 used) -> 128 B stride

__global__ __launch_bounds__(THREADS) void se3_build_table(
    const float* __restrict__ W1,   // (10, 64)
    const float* __restrict__ W2,   // (64, 384)
    __half* __restrict__ T)         // (RTAB, ROWH) halves
{
    __shared__ float sW1[10 * 65];
    for (int t = threadIdx.x; t < 640; t += THREADS) {
        int j = t >> 6, k = t & 63;
        sW1[j * 65 + k] = W1[t];
    }
    __syncthreads();

    int g = blockIdx.x * THREADS + threadIdx.x;
    if (g >= RTAB * 24) return;
    int i = g / 24;
    int j = g - i * 24;        // j = u*3 + c
    int u = j / 3, c = j - u * 3;

    float r = 3.0f * (float)i / (float)(RTAB - 1);

    float psi = 0.0f;
    float t10 = 10.0f - (10.0f / 3.0f) * r;
    if (t10 > 0.0f) {
        // radial bump embedding: at most 2 of 10 basis functions non-zero.
        // C0 = 1.14136*e^2 (sqrt(10) norms cancel between emb and W1).
        const float C0 = 8.43357306907549f;
        float q  = r * (11.0f / 3.0f);
        int   jf = (int)q;
        float da = q - (float)jf;
        float db = da - 1.0f;
        float ya = fmaxf(1.0f - da * da, 1e-7f);
        float yb = fmaxf(1.0f - db * db, 1e-7f);
        int ja = jf - 1, jb = jf;
        float ea = (ja >= 0) ? C0 * __expf(-1.0f / ya) : 0.0f;
        float eb = (jb <= 9) ? C0 * __expf(-1.0f / yb) : 0.0f;
        int jac = ja < 0 ? 0 : ja;
        int jbc = jb > 9 ? 9 : jb;
        const float* w1a = sW1 + jac * 65;
        const float* w1b = sW1 + jbc * 65;
        const float* w2  = W2 + u * 32 + c;

        float acc = 0.0f;
#pragma unroll 8
        for (int k = 0; k < 64; ++k) {
            float pre = ea * w1a[k] + eb * w1b[k];
            float h   = pre * __builtin_amdgcn_rcpf(1.0f + __expf(-pre)); // silu
            acc += h * w2[k * 384];
        }
        // fold cutoff and 1/(8*sqrt(8))
        psi = acc * __expf(-1.0f / t10) * 0.04419417382415922f;
    }

    __half hv = __float2half(psi);
    T[(size_t)i * ROWH + 2 * j] = hv;                    // row i, .x endpoint
    if (i > 0) T[(size_t)(i - 1) * ROWH + 2 * j + 1] = hv; // row i-1, .y endpoint
}

__global__ __launch_bounds__(THREADS) void se3_edge_kernel(
    const float* __restrict__ x,     // (B*N, 8)
    const float* __restrict__ pos,   // (B*N, 3)
    const int*   __restrict__ esrc,  // (E,)
    const int*   __restrict__ edst,  // (E,)
    const __half* __restrict__ T,    // (RTAB, ROWH)
    float*       __restrict__ outbuf,// ncopies x outN, pre-zeroed
    int E, int ncopies, int outN)
{
    int e = blockIdx.x * THREADS + threadIdx.x;
    if (e >= E) return;

    int s = esrc[e];
    int d = edst[e];

    float ex = pos[3 * s + 0] - pos[3 * d + 0];
    float ey = pos[3 * s + 1] - pos[3 * d + 1];
    float ez = pos[3 * s + 2] - pos[3 * d + 2];
    float r  = sqrtf(ex * ex + ey * ey + ez * ez + 1e-18f);

    if (r >= 3.0f) return;   // wcut == 0 -> edge contributes nothing

    float tq = r * ((float)(RTAB - 1) / 3.0f);
    int   i  = (int)tq;
    if (i > RTAB - 2) i = RTAB - 2;
    float f  = tq - (float)i;

    const float4* rowp = reinterpret_cast<const float4*>(T + (size_t)i * ROWH);
    const float4* xf   = reinterpret_cast<const float4*>(x + 8 * (size_t)s);
    float4 xA = xf[0];
    float4 xB = xf[1];
    float xs[8] = {xA.x, xA.y, xA.z, xA.w, xB.x, xB.y, xB.z, xB.w};

    float p[3] = {0.0f, 0.0f, 0.0f};
#pragma unroll
    for (int qi = 0; qi < 6; ++qi) {
        float4 v = rowp[qi];
        const __half2* h2 = reinterpret_cast<const __half2*>(&v);
#pragma unroll
        for (int m = 0; m < 4; ++m) {
            int j = 4 * qi + m;          // compile-time
            int u = j / 3, c = j - 3 * u;
            float2 ab = __half22float2(h2[m]);
            float val = fmaf(f, ab.y - ab.x, ab.x);
            p[c] = fmaf(xs[u], val, p[c]);
        }
    }

    // curl folded in: curl = (psi2-psi1, psi0-psi2, psi1-psi0)
    float* ob = outbuf + (size_t)(blockIdx.x % ncopies) * outN + 3 * d;
    atomicAdd(ob + 0, p[2] - p[1]);
    atomicAdd(ob + 1, p[0] - p[2]);
    atomicAdd(ob + 2, p[1] - p[0]);
}

__global__ __launch_bounds__(THREADS) void se3_reduce_kernel(
    const float* __restrict__ ws, float* __restrict__ out,
    int outN4, int ncopies)
{
    int idx = blockIdx.x * THREADS + threadIdx.x;
    if (idx >= outN4) return;
    const float4* w = reinterpret_cast<const float4*>(ws);
    float4 acc = w[idx];
    for (int c = 1; c < ncopies; ++c) {
        float4 v = w[(size_t)c * outN4 + idx];
        acc.x += v.x; acc.y += v.y; acc.z += v.z; acc.w += v.w;
    }
    reinterpret_cast<float4*>(out)[idx] = acc;
}

extern "C" void kernel_launch(void* const* d_in, const int* in_sizes, int n_in,
                              void* d_out, int out_size, void* d_ws, size_t ws_size,
                              hipStream_t stream) {
    const float* x    = (const float*)d_in[0];
    const float* pos  = (const float*)d_in[1];
    const int*   esrc = (const int*)d_in[2];
    const int*   edst = (const int*)d_in[3];
    const float* W1   = (const float*)d_in[4];
    const float* W2   = (const float*)d_in[5];
    float* out = (float*)d_out;

    int E    = in_sizes[2];
    int outN = out_size;  // B*N*3

    size_t tableBytes = (size_t)RTAB * ROWH * sizeof(__half);  // 256 KB
    __half* T = (__half*)d_ws;

    int ncopies = 1;
    if (ws_size > tableBytes) {
        size_t rem = ws_size - tableBytes;
        int nc = (int)(rem / ((size_t)outN * sizeof(float)));
        if (nc > 8) nc = 8;
        if (nc < 1) nc = 1;
        ncopies = nc;
    }

    int buildBlocks = (RTAB * 24 + THREADS - 1) / THREADS;
    se3_build_table<<<buildBlocks, THREADS, 0, stream>>>(W1, W2, T);

    int edgeBlocks = (E + THREADS - 1) / THREADS;
    if (ncopies >= 2) {
        float* copies = (float*)((char*)d_ws + tableBytes);
        hipMemsetAsync(copies, 0, (size_t)ncopies * outN * sizeof(float), stream);
        se3_edge_kernel<<<edgeBlocks, THREADS, 0, stream>>>(
            x, pos, esrc, edst, T, copies, E, ncopies, outN);
        int outN4 = outN / 4;
        se3_reduce_kernel<<<(outN4 + THREADS - 1) / THREADS, THREADS, 0, stream>>>(
            copies, out, outN4, ncopies);
    } else {
        hipMemsetAsync(out, 0, (size_t)outN * sizeof(float), stream);
        se3_edge_kernel<<<edgeBlocks, THREADS, 0, stream>>>(
            x, pos, esrc, edst, T, out, E, 1, outN);
    }
}